// Round 15
// baseline (40.229 us; speedup 1.0000x reference)
//
#include <hip/hip_runtime.h>

// Problem constants (from reference)
#define B 8
#define C 64
#define H 64
#define W 64
#define K 5
#define PAD 2
#define HW (H * W)          // 4096
#define CHW (C * HW)        // 262144
#define TOT (B * CHW)       // 2097152

// attn tiling: tile = 16 rows x 64 cols; block = one (b,c) plane, 4 tiles
#define TROWS 16
#define SROWS (TROWS + 2 * PAD)   // 20 staged rows
#define SCOLS 72                  // 64 + 2*PAD, padded to 72 for 16B row alignment
#define NSLOT2 (SROWS * (SCOLS / 2))  // 720 float2 slots per plane

#define LOG2E 1.44269504088896340736f

typedef __attribute__((ext_vector_type(8))) short short8;   // 8 bf16 = 4 VGPR
typedef __attribute__((ext_vector_type(4))) float f32x4;    // mfma accum

__device__ inline unsigned short f2bf(float f) {            // fp32 -> bf16 RNE
    unsigned u = __float_as_uint(f);
    u = u + 0x7fffu + ((u >> 16) & 1u);
    return (unsigned short)(u >> 16);
}
__device__ inline float bf2f(unsigned short h) {
    return __uint_as_float(((unsigned)h) << 16);
}

// ---------------------------------------------------------------------------
// Pass 1 (v8): qkv MFMA GEMM, XCD-swizzled grid — byte-identical to r12
// (the 32.2 us best config).
// ---------------------------------------------------------------------------
__global__ __launch_bounds__(256) void qkv_mfma(
    const float* __restrict__ x,
    const float* __restrict__ Wq,
    const float* __restrict__ Wk,
    const float* __restrict__ Wv,
    float* __restrict__ qb, float* __restrict__ kb, float* __restrict__ vb)
{
    __shared__ unsigned short sxh[32][72];   // [n][k], 4.6 KB
    __shared__ unsigned short sxl[32][72];

    const int bid = blockIdx.x;
    const int b   = bid & 7;             // XCD co-residency: batch = XCD
    const int n0  = (bid >> 3) * 32;     // hw base (128 chunks per batch)
    const int t   = threadIdx.x;

    const float* xb = x + b * CHW;
#pragma unroll
    for (int i = 0; i < 2; ++i) {
        const int flat = t + i * 256;        // 0..511
        const int k    = flat >> 3;          // 8 float4 per k-row of 32
        const int n4   = (flat & 7) << 2;
        const float4 v = *(const float4*)(xb + k * HW + n0 + n4);
        const float vv[4] = {v.x, v.y, v.z, v.w};
#pragma unroll
        for (int j = 0; j < 4; ++j) {
            const unsigned short h = f2bf(vv[j]);
            sxh[n4 + j][k] = h;
            sxl[n4 + j][k] = f2bf(vv[j] - bf2f(h));
        }
    }
    __syncthreads();

    const int lane = t & 63;
    const int wv   = __builtin_amdgcn_readfirstlane(t >> 6);  // wave id 0..3
    const int lr   = lane & 15;          // tile row (A) / col (B,D)
    const int lk   = (lane >> 4) * 8;    // k-group base

    short8 ah[3][2], al[3][2];
#pragma unroll
    for (int ot = 0; ot < 3; ++ot) {
        const int tile = wv * 3 + ot;            // 0..11
        const int m    = tile >> 2;              // 0=q,1=k,2=v
        const int ol0  = (tile & 3) * 16;        // o base within matrix
        const float* Wm = (m == 0) ? Wq : (m == 1) ? Wk : Wv;
        const float* wrow = Wm + (ol0 + lr) * 64;
#pragma unroll
        for (int ks = 0; ks < 2; ++ks) {
            const float4 w0 = *(const float4*)(wrow + lk + ks * 32);
            const float4 w1 = *(const float4*)(wrow + lk + ks * 32 + 4);
            const float wv8[8] = {w0.x, w0.y, w0.z, w0.w,
                                  w1.x, w1.y, w1.z, w1.w};
            short8 hi, lo;
#pragma unroll
            for (int j = 0; j < 8; ++j) {
                const unsigned short hh = f2bf(wv8[j]);
                hi[j] = (short)hh;
                lo[j] = (short)f2bf(wv8[j] - bf2f(hh));
            }
            ah[ot][ks] = hi;
            al[ot][ks] = lo;
        }
    }

    f32x4 acc[3][2];
#pragma unroll
    for (int ot = 0; ot < 3; ++ot)
#pragma unroll
        for (int nt = 0; nt < 2; ++nt) acc[ot][nt] = (f32x4)0.f;

#pragma unroll
    for (int nt = 0; nt < 2; ++nt) {
        const short8 bh0 = *(const short8*)&sxh[nt * 16 + lr][lk];
        const short8 bh1 = *(const short8*)&sxh[nt * 16 + lr][32 + lk];
        const short8 bl0 = *(const short8*)&sxl[nt * 16 + lr][lk];
        const short8 bl1 = *(const short8*)&sxl[nt * 16 + lr][32 + lk];
#pragma unroll
        for (int ot = 0; ot < 3; ++ot) {
            f32x4 d = acc[ot][nt];
            d = __builtin_amdgcn_mfma_f32_16x16x32_bf16(ah[ot][0], bh0, d, 0, 0, 0);
            d = __builtin_amdgcn_mfma_f32_16x16x32_bf16(ah[ot][1], bh1, d, 0, 0, 0);
            d = __builtin_amdgcn_mfma_f32_16x16x32_bf16(ah[ot][0], bl0, d, 0, 0, 0);
            d = __builtin_amdgcn_mfma_f32_16x16x32_bf16(ah[ot][1], bl1, d, 0, 0, 0);
            d = __builtin_amdgcn_mfma_f32_16x16x32_bf16(al[ot][0], bh0, d, 0, 0, 0);
            d = __builtin_amdgcn_mfma_f32_16x16x32_bf16(al[ot][1], bh1, d, 0, 0, 0);
            acc[ot][nt] = d;
        }
    }

#pragma unroll
    for (int ot = 0; ot < 3; ++ot) {
        const int tile = wv * 3 + ot;
        const int m    = tile >> 2;
        const int ol0  = (tile & 3) * 16;
        float* ob = (m == 0) ? qb : (m == 1) ? kb : vb;
        float* basep = ob + b * CHW + ol0 * HW + n0;
#pragma unroll
        for (int nt = 0; nt < 2; ++nt)
#pragma unroll
            for (int r = 0; r < 4; ++r) {
                const int orow = (lane >> 4) * 4 + r;
                basep[orow * HW + nt * 16 + lr] = acc[ot][nt][r];
            }
    }
}

// ---------------------------------------------------------------------------
// Pass 2 (v4): attn, 4x fewer workgroups.  Block = one (b,c) plane (512
// wgs, bid = c*8 + b keeps XCD co-residency), looping over 4 row-tiles
// with DOUBLE-BUFFERED LDS: stage tile t+1 while computing tile t, one
// barrier per tile.  Per-tile compute body identical to r13 (exp2).
// Probe r11/r13 showed ~9.7 ns/WG fixed cost for both kernels -> wg-count
// is the hypothesized governing term; this tests and exploits it.
// ---------------------------------------------------------------------------
__global__ __launch_bounds__(256) void attn_kernel(
    const float* __restrict__ qb,
    const float* __restrict__ kb,
    const float* __restrict__ vb,
    const float* __restrict__ rel_h,
    const float* __restrict__ rel_w,
    float* __restrict__ out)
{
    __shared__ __align__(16) float sk[2][SROWS][SCOLS];   // 11.5 KB
    __shared__ __align__(16) float sv[2][SROWS][SCOLS];   // 11.5 KB

    const int bid = blockIdx.x;
    const int b   = bid & 7;           // XCD co-residency: batch = XCD
    const int c   = bid >> 3;          // 0..63
    const int pl  = b * C + c;
    const int t   = threadIdx.x;

    const float* kp = kb + pl * HW;
    const float* vp = vb + pl * HW;

    // stage tile `tt` (rows tt*16-2 .. tt*16+17) into buffer `bf`
    auto stage = [&](int bf, int tt) {
        const int h0 = tt * TROWS;
        for (int idx = t; idx < 2 * NSLOT2; idx += 256) {
            const int p   = (idx >= NSLOT2);
            const int rem = p ? idx - NSLOT2 : idx;
            const int row = rem / (SCOLS / 2);
            const int c2  = rem - row * (SCOLS / 2);   // float2 col 0..35
            const int g   = h0 + row - PAD;            // global row
            float2 val = make_float2(0.f, 0.f);
            if (((unsigned)g < (unsigned)H) & (c2 >= 1) & (c2 <= 32)) {
                const float* src = (p ? vp : kp) + g * W + (c2 * 2 - 2);
                val = *(const float2*)src;
            }
            float* dst = (p ? &sv[bf][0][0] : &sk[bf][0][0]) + row * SCOLS + c2 * 2;
            *(float2*)dst = val;
        }
    };

    const bool is_h = (c < (C / 2));
    const float* rp = is_h ? (rel_h + c * K) : (rel_w + (c - C / 2) * K);
    float r[K];
#pragma unroll
    for (int u2 = 0; u2 < K; ++u2) r[u2] = rp[u2];

    const int lr = t >> 4;             // local row 0..15
    const int w0 = (t & 15) << 2;      // col base 0,4,..,60

    stage(0, 0);
    __syncthreads();

    for (int t4 = 0; t4 < 4; ++t4) {
        const int cur = t4 & 1;
        if (t4 < 3) stage(cur ^ 1, t4 + 1);     // overlap with compute below

        const int h = t4 * TROWS + lr;

        const float4 qv = *(const float4*)(qb + pl * HW + h * W + w0);
        const float qe[4] = {qv.x * LOG2E, qv.y * LOG2E,
                             qv.z * LOG2E, qv.w * LOG2E};

        float den[4] = {0.f, 0.f, 0.f, 0.f};
        float num[4] = {0.f, 0.f, 0.f, 0.f};

        if (is_h) {
#pragma unroll
            for (int i = 0; i < K; ++i) {
                const float4 ka = *(const float4*)&sk[cur][lr + i][w0];
                const float4 kc = *(const float4*)&sk[cur][lr + i][w0 + 4];
                const float4 va = *(const float4*)&sv[cur][lr + i][w0];
                const float4 vc = *(const float4*)&sv[cur][lr + i][w0 + 4];
                const float kr[8] = {ka.x, ka.y, ka.z, ka.w, kc.x, kc.y, kc.z, kc.w};
                const float vr[8] = {va.x, va.y, va.z, va.w, vc.x, vc.y, vc.z, vc.w};
                float qri[4];
#pragma unroll
                for (int px = 0; px < 4; ++px) qri[px] = qe[px] * r[i];
#pragma unroll
                for (int j = 0; j < K; ++j) {
#pragma unroll
                    for (int px = 0; px < 4; ++px) {
                        const float e = exp2f(fmaf(qe[px], kr[px + j], qri[px]));
                        den[px] += e;
                        num[px] = fmaf(e, vr[px + j], num[px]);
                    }
                }
            }
        } else {
            float qrj[4][K];
#pragma unroll
            for (int px = 0; px < 4; ++px)
#pragma unroll
                for (int j = 0; j < K; ++j) qrj[px][j] = qe[px] * r[j];
#pragma unroll
            for (int i = 0; i < K; ++i) {
                const float4 ka = *(const float4*)&sk[cur][lr + i][w0];
                const float4 kc = *(const float4*)&sk[cur][lr + i][w0 + 4];
                const float4 va = *(const float4*)&sv[cur][lr + i][w0];
                const float4 vc = *(const float4*)&sv[cur][lr + i][w0 + 4];
                const float kr[8] = {ka.x, ka.y, ka.z, ka.w, kc.x, kc.y, kc.z, kc.w};
                const float vr[8] = {va.x, va.y, va.z, va.w, vc.x, vc.y, vc.z, vc.w};
#pragma unroll
                for (int j = 0; j < K; ++j) {
#pragma unroll
                    for (int px = 0; px < 4; ++px) {
                        const float e = exp2f(fmaf(qe[px], kr[px + j], qrj[px][j]));
                        den[px] += e;
                        num[px] = fmaf(e, vr[px + j], num[px]);
                    }
                }
            }
        }

        float4 o;
        o.x = num[0] * __builtin_amdgcn_rcpf(den[0]);
        o.y = num[1] * __builtin_amdgcn_rcpf(den[1]);
        o.z = num[2] * __builtin_amdgcn_rcpf(den[2]);
        o.w = num[3] * __builtin_amdgcn_rcpf(den[3]);
        *(float4*)(out + pl * HW + h * W + w0) = o;

        __syncthreads();   // stage(t4+1) complete + all reads of buf done
    }
}

// ---------------------------------------------------------------------------
extern "C" void kernel_launch(void* const* d_in, const int* in_sizes, int n_in,
                              void* d_out, int out_size, void* d_ws, size_t ws_size,
                              hipStream_t stream)
{
    const float* x     = (const float*)d_in[0];
    const float* Wq    = (const float*)d_in[1];
    const float* Wk    = (const float*)d_in[2];
    const float* Wv    = (const float*)d_in[3];
    const float* rel_h = (const float*)d_in[4];
    const float* rel_w = (const float*)d_in[5];

    float* qb = (float*)d_ws;        // [B,C,64,64]  8 MB
    float* kb = qb + TOT;            // [B,C,64,64]  8 MB
    float* vb = kb + TOT;            // [B,C,64,64]  8 MB

    qkv_mfma<<<B * 128, 256, 0, stream>>>(x, Wq, Wk, Wv, qb, kb, vb);

    attn_kernel<<<B * C, 256, 0, stream>>>(qb, kb, vb, rel_h, rel_w,
                                           (float*)d_out);
}

// Round 16
// 31.241 us; speedup vs baseline: 1.2877x; 1.2877x over previous
//
#include <hip/hip_runtime.h>

// Problem constants (from reference)
#define B 8
#define C 64
#define H 64
#define W 64
#define K 5
#define PAD 2
#define HW (H * W)          // 4096
#define CHW (C * HW)        // 262144
#define TOT (B * CHW)       // 2097152

// attn tiling: block = 16 rows x 64 cols of one (b,c) plane
#define TROWS 16
#define SROWS (TROWS + 2 * PAD)   // 20 staged rows
#define SCOLS 72                  // 64 + 2*PAD, padded to 72 for 16B row alignment
#define NSLOT2 (SROWS * (SCOLS / 2))  // 720 float2 slots per plane

#define LOG2E 1.44269504088896340736f

typedef __attribute__((ext_vector_type(8))) short short8;   // 8 bf16 = 4 VGPR
typedef __attribute__((ext_vector_type(4))) float f32x4;    // mfma accum

__device__ inline unsigned short f2bf(float f) {            // fp32 -> bf16 RNE
    unsigned u = __float_as_uint(f);
    u = u + 0x7fffu + ((u >> 16) & 1u);
    return (unsigned short)(u >> 16);
}
__device__ inline float bf2f(unsigned short h) {
    return __uint_as_float(((unsigned)h) << 16);
}

// raw v_exp_f32 — exp2f() is the PRECISE libm call and lowers to a guarded
// multi-instruction sequence under default denormal mode; the builtin is one
// instruction. Inputs here are in [-40, 40], well inside v_exp's domain.
__device__ inline float fast_exp2(float x) {
    return __builtin_amdgcn_exp2f(x);
}

// ---------------------------------------------------------------------------
// Pass 1 (v8): qkv MFMA GEMM, XCD-swizzled grid — byte-identical to r12
// (the 32.2 us best config).
// ---------------------------------------------------------------------------
__global__ __launch_bounds__(256) void qkv_mfma(
    const float* __restrict__ x,
    const float* __restrict__ Wq,
    const float* __restrict__ Wk,
    const float* __restrict__ Wv,
    float* __restrict__ qb, float* __restrict__ kb, float* __restrict__ vb)
{
    __shared__ unsigned short sxh[32][72];   // [n][k], 4.6 KB
    __shared__ unsigned short sxl[32][72];

    const int bid = blockIdx.x;
    const int b   = bid & 7;             // XCD co-residency: batch = XCD
    const int n0  = (bid >> 3) * 32;     // hw base (128 chunks per batch)
    const int t   = threadIdx.x;

    const float* xb = x + b * CHW;
#pragma unroll
    for (int i = 0; i < 2; ++i) {
        const int flat = t + i * 256;        // 0..511
        const int k    = flat >> 3;          // 8 float4 per k-row of 32
        const int n4   = (flat & 7) << 2;
        const float4 v = *(const float4*)(xb + k * HW + n0 + n4);
        const float vv[4] = {v.x, v.y, v.z, v.w};
#pragma unroll
        for (int j = 0; j < 4; ++j) {
            const unsigned short h = f2bf(vv[j]);
            sxh[n4 + j][k] = h;
            sxl[n4 + j][k] = f2bf(vv[j] - bf2f(h));
        }
    }
    __syncthreads();

    const int lane = t & 63;
    const int wv   = __builtin_amdgcn_readfirstlane(t >> 6);  // wave id 0..3
    const int lr   = lane & 15;          // tile row (A) / col (B,D)
    const int lk   = (lane >> 4) * 8;    // k-group base

    short8 ah[3][2], al[3][2];
#pragma unroll
    for (int ot = 0; ot < 3; ++ot) {
        const int tile = wv * 3 + ot;            // 0..11
        const int m    = tile >> 2;              // 0=q,1=k,2=v
        const int ol0  = (tile & 3) * 16;        // o base within matrix
        const float* Wm = (m == 0) ? Wq : (m == 1) ? Wk : Wv;
        const float* wrow = Wm + (ol0 + lr) * 64;
#pragma unroll
        for (int ks = 0; ks < 2; ++ks) {
            const float4 w0 = *(const float4*)(wrow + lk + ks * 32);
            const float4 w1 = *(const float4*)(wrow + lk + ks * 32 + 4);
            const float wv8[8] = {w0.x, w0.y, w0.z, w0.w,
                                  w1.x, w1.y, w1.z, w1.w};
            short8 hi, lo;
#pragma unroll
            for (int j = 0; j < 8; ++j) {
                const unsigned short hh = f2bf(wv8[j]);
                hi[j] = (short)hh;
                lo[j] = (short)f2bf(wv8[j] - bf2f(hh));
            }
            ah[ot][ks] = hi;
            al[ot][ks] = lo;
        }
    }

    f32x4 acc[3][2];
#pragma unroll
    for (int ot = 0; ot < 3; ++ot)
#pragma unroll
        for (int nt = 0; nt < 2; ++nt) acc[ot][nt] = (f32x4)0.f;

#pragma unroll
    for (int nt = 0; nt < 2; ++nt) {
        const short8 bh0 = *(const short8*)&sxh[nt * 16 + lr][lk];
        const short8 bh1 = *(const short8*)&sxh[nt * 16 + lr][32 + lk];
        const short8 bl0 = *(const short8*)&sxl[nt * 16 + lr][lk];
        const short8 bl1 = *(const short8*)&sxl[nt * 16 + lr][32 + lk];
#pragma unroll
        for (int ot = 0; ot < 3; ++ot) {
            f32x4 d = acc[ot][nt];
            d = __builtin_amdgcn_mfma_f32_16x16x32_bf16(ah[ot][0], bh0, d, 0, 0, 0);
            d = __builtin_amdgcn_mfma_f32_16x16x32_bf16(ah[ot][1], bh1, d, 0, 0, 0);
            d = __builtin_amdgcn_mfma_f32_16x16x32_bf16(ah[ot][0], bl0, d, 0, 0, 0);
            d = __builtin_amdgcn_mfma_f32_16x16x32_bf16(ah[ot][1], bl1, d, 0, 0, 0);
            d = __builtin_amdgcn_mfma_f32_16x16x32_bf16(al[ot][0], bh0, d, 0, 0, 0);
            d = __builtin_amdgcn_mfma_f32_16x16x32_bf16(al[ot][1], bh1, d, 0, 0, 0);
            acc[ot][nt] = d;
        }
    }

#pragma unroll
    for (int ot = 0; ot < 3; ++ot) {
        const int tile = wv * 3 + ot;
        const int m    = tile >> 2;
        const int ol0  = (tile & 3) * 16;
        float* ob = (m == 0) ? qb : (m == 1) ? kb : vb;
        float* basep = ob + b * CHW + ol0 * HW + n0;
#pragma unroll
        for (int nt = 0; nt < 2; ++nt)
#pragma unroll
            for (int r = 0; r < 4; ++r) {
                const int orow = (lane >> 4) * 4 + r;
                basep[orow * HW + nt * 16 + lr] = acc[ot][nt][r];
            }
    }
}

// ---------------------------------------------------------------------------
// Pass 2 (v5): attn, r12 structure (2048 wgs = full 32 waves/CU occupancy —
// best measured) with RAW v_exp_f32 via builtin (exp2f was lowering to a
// guarded multi-op sequence; ~100 exps/thread made that ~25% of the kernel).
// ---------------------------------------------------------------------------
__global__ __launch_bounds__(256) void attn_kernel(
    const float* __restrict__ qb,
    const float* __restrict__ kb,
    const float* __restrict__ vb,
    const float* __restrict__ rel_h,
    const float* __restrict__ rel_w,
    float* __restrict__ out)
{
    __shared__ __align__(16) float sk[SROWS][SCOLS];
    __shared__ __align__(16) float sv[SROWS][SCOLS];

    const int bid = blockIdx.x;
    const int b   = bid & 7;           // XCD co-residency: batch = XCD
    const int u   = bid >> 3;          // 0..255: chan*4 + rowtile
    const int c   = u >> 2;
    const int pl  = b * C + c;
    const int h0  = (u & 3) * TROWS;
    const int t   = threadIdx.x;

    const float* kp = kb + pl * HW;
    const float* vp = vb + pl * HW;

    // ---- stage: 2 planes * 720 float2 slots ----
    for (int idx = t; idx < 2 * NSLOT2; idx += 256) {
        const int p   = (idx >= NSLOT2);
        const int rem = p ? idx - NSLOT2 : idx;
        const int row = rem / (SCOLS / 2);
        const int c2  = rem - row * (SCOLS / 2);   // float2 col 0..35
        const int g   = h0 + row - PAD;            // global row
        float2 val = make_float2(0.f, 0.f);
        if (((unsigned)g < (unsigned)H) & (c2 >= 1) & (c2 <= 32)) {
            const float* src = (p ? vp : kp) + g * W + (c2 * 2 - 2);
            val = *(const float2*)src;
        }
        float* dst = (p ? &sv[0][0] : &sk[0][0]) + row * SCOLS + c2 * 2;
        *(float2*)dst = val;
    }
    __syncthreads();

    // ---- compute: 1 quad (4 px) per thread ----
    const int lr = t >> 4;             // local row 0..15
    const int w0 = (t & 15) << 2;      // col base 0,4,..,60
    const int h  = h0 + lr;

    const float4 qv = *(const float4*)(qb + pl * HW + h * W + w0);
    const float qe[4] = {qv.x * LOG2E, qv.y * LOG2E, qv.z * LOG2E, qv.w * LOG2E};

    const bool is_h = (c < (C / 2));
    const float* rp = is_h ? (rel_h + c * K) : (rel_w + (c - C / 2) * K);
    float r[K];
#pragma unroll
    for (int u2 = 0; u2 < K; ++u2) r[u2] = rp[u2];

    float den[4] = {0.f, 0.f, 0.f, 0.f};
    float num[4] = {0.f, 0.f, 0.f, 0.f};

    if (is_h) {
#pragma unroll
        for (int i = 0; i < K; ++i) {
            const float4 ka = *(const float4*)&sk[lr + i][w0];
            const float4 kc = *(const float4*)&sk[lr + i][w0 + 4];
            const float4 va = *(const float4*)&sv[lr + i][w0];
            const float4 vc = *(const float4*)&sv[lr + i][w0 + 4];
            const float kr[8] = {ka.x, ka.y, ka.z, ka.w, kc.x, kc.y, kc.z, kc.w};
            const float vr[8] = {va.x, va.y, va.z, va.w, vc.x, vc.y, vc.z, vc.w};
            float qri[4];
#pragma unroll
            for (int px = 0; px < 4; ++px) qri[px] = qe[px] * r[i];
#pragma unroll
            for (int j = 0; j < K; ++j) {
#pragma unroll
                for (int px = 0; px < 4; ++px) {
                    const float e = fast_exp2(fmaf(qe[px], kr[px + j], qri[px]));
                    den[px] += e;
                    num[px] = fmaf(e, vr[px + j], num[px]);
                }
            }
        }
    } else {
        float qrj[4][K];
#pragma unroll
        for (int px = 0; px < 4; ++px)
#pragma unroll
            for (int j = 0; j < K; ++j) qrj[px][j] = qe[px] * r[j];
#pragma unroll
        for (int i = 0; i < K; ++i) {
            const float4 ka = *(const float4*)&sk[lr + i][w0];
            const float4 kc = *(const float4*)&sk[lr + i][w0 + 4];
            const float4 va = *(const float4*)&sv[lr + i][w0];
            const float4 vc = *(const float4*)&sv[lr + i][w0 + 4];
            const float kr[8] = {ka.x, ka.y, ka.z, ka.w, kc.x, kc.y, kc.z, kc.w};
            const float vr[8] = {va.x, va.y, va.z, va.w, vc.x, vc.y, vc.z, vc.w};
#pragma unroll
            for (int j = 0; j < K; ++j) {
#pragma unroll
                for (int px = 0; px < 4; ++px) {
                    const float e = fast_exp2(fmaf(qe[px], kr[px + j], qrj[px][j]));
                    den[px] += e;
                    num[px] = fmaf(e, vr[px + j], num[px]);
                }
            }
        }
    }

    float4 o;
    o.x = num[0] * __builtin_amdgcn_rcpf(den[0]);
    o.y = num[1] * __builtin_amdgcn_rcpf(den[1]);
    o.z = num[2] * __builtin_amdgcn_rcpf(den[2]);
    o.w = num[3] * __builtin_amdgcn_rcpf(den[3]);
    *(float4*)(out + pl * HW + h * W + w0) = o;
}

// ---------------------------------------------------------------------------
extern "C" void kernel_launch(void* const* d_in, const int* in_sizes, int n_in,
                              void* d_out, int out_size, void* d_ws, size_t ws_size,
                              hipStream_t stream)
{
    const float* x     = (const float*)d_in[0];
    const float* Wq    = (const float*)d_in[1];
    const float* Wk    = (const float*)d_in[2];
    const float* Wv    = (const float*)d_in[3];
    const float* rel_h = (const float*)d_in[4];
    const float* rel_w = (const float*)d_in[5];

    float* qb = (float*)d_ws;        // [B,C,64,64]  8 MB
    float* kb = qb + TOT;            // [B,C,64,64]  8 MB
    float* vb = kb + TOT;            // [B,C,64,64]  8 MB

    qkv_mfma<<<B * 128, 256, 0, stream>>>(x, Wq, Wk, Wv, qb, kb, vb);

    attn_kernel<<<B * C * 4, 256, 0, stream>>>(qb, kb, vb, rel_h, rel_w,
                                               (float*)d_out);
}

// Round 17
// 28.861 us; speedup vs baseline: 1.3939x; 1.0825x over previous
//
#include <hip/hip_runtime.h>
#include <hip/hip_bf16.h>

// Problem constants (from reference)
#define B 8
#define C 64
#define H 64
#define W 64
#define K 5
#define PAD 2
#define HW (H * W)          // 4096
#define CHW (C * HW)        // 262144
#define TOT (B * CHW)       // 2097152

// attn tiling: block = 16 rows x 64 cols of one (b,c) plane
#define TROWS 16
#define SROWS (TROWS + 2 * PAD)   // 20 staged rows
#define SCOLS 72                  // 64 + 2*PAD, padded to 72 for 16B row alignment

#define LOG2E 1.44269504088896340736f

typedef __attribute__((ext_vector_type(8))) short short8;   // 8 bf16 = 4 VGPR
typedef __attribute__((ext_vector_type(4))) float f32x4;    // mfma accum

// native bf16 conversion (RNE; compiler emits v_cvt_pk_bf16_f32 for pairs)
__device__ inline unsigned short f2bf(float f) {
    __hip_bfloat16 h = __float2bfloat16(f);
    return *(unsigned short*)&h;
}
__device__ inline float bf2f(unsigned short u) {
    return __uint_as_float(((unsigned)u) << 16);
}

// raw v_exp_f32 (single instruction; inputs here are in [-40,40])
__device__ inline float fast_exp2(float x) {
    return __builtin_amdgcn_exp2f(x);
}

// ---------------------------------------------------------------------------
// Pass 1 (v10): qkv MFMA GEMM, XCD-swizzled grid — r12 structure with
// native bf16 cvt replacing the 4-op manual RNE bit-twiddle (~200 VALU/thr
// -> ~50).  Out[192,HW] = W[192,64] @ x[64,HW] per b; fp32 emulated as
// Wh*xh + Wh*xl + Wl*xh.
// ---------------------------------------------------------------------------
__global__ __launch_bounds__(256) void qkv_mfma(
    const float* __restrict__ x,
    const float* __restrict__ Wq,
    const float* __restrict__ Wk,
    const float* __restrict__ Wv,
    float* __restrict__ qb, float* __restrict__ kb, float* __restrict__ vb)
{
    __shared__ unsigned short sxh[32][72];   // [n][k], 4.6 KB
    __shared__ unsigned short sxl[32][72];

    const int bid = blockIdx.x;
    const int b   = bid & 7;             // XCD co-residency: batch = XCD
    const int n0  = (bid >> 3) * 32;     // hw base (128 chunks per batch)
    const int t   = threadIdx.x;

    const float* xb = x + b * CHW;
#pragma unroll
    for (int i = 0; i < 2; ++i) {
        const int flat = t + i * 256;        // 0..511
        const int k    = flat >> 3;          // 8 float4 per k-row of 32
        const int n4   = (flat & 7) << 2;
        const float4 v = *(const float4*)(xb + k * HW + n0 + n4);
        const float vv[4] = {v.x, v.y, v.z, v.w};
#pragma unroll
        for (int j = 0; j < 4; ++j) {
            const unsigned short h = f2bf(vv[j]);
            sxh[n4 + j][k] = h;
            sxl[n4 + j][k] = f2bf(vv[j] - bf2f(h));
        }
    }
    __syncthreads();

    const int lane = t & 63;
    const int wv   = __builtin_amdgcn_readfirstlane(t >> 6);  // wave id 0..3
    const int lr   = lane & 15;          // tile row (A) / col (B,D)
    const int lk   = (lane >> 4) * 8;    // k-group base

    short8 ah[3][2], al[3][2];
#pragma unroll
    for (int ot = 0; ot < 3; ++ot) {
        const int tile = wv * 3 + ot;            // 0..11
        const int m    = tile >> 2;              // 0=q,1=k,2=v
        const int ol0  = (tile & 3) * 16;        // o base within matrix
        const float* Wm = (m == 0) ? Wq : (m == 1) ? Wk : Wv;
        const float* wrow = Wm + (ol0 + lr) * 64;
#pragma unroll
        for (int ks = 0; ks < 2; ++ks) {
            const float4 w0 = *(const float4*)(wrow + lk + ks * 32);
            const float4 w1 = *(const float4*)(wrow + lk + ks * 32 + 4);
            const float wv8[8] = {w0.x, w0.y, w0.z, w0.w,
                                  w1.x, w1.y, w1.z, w1.w};
            short8 hi, lo;
#pragma unroll
            for (int j = 0; j < 8; ++j) {
                const unsigned short hh = f2bf(wv8[j]);
                hi[j] = (short)hh;
                lo[j] = (short)f2bf(wv8[j] - bf2f(hh));
            }
            ah[ot][ks] = hi;
            al[ot][ks] = lo;
        }
    }

    f32x4 acc[3][2];
#pragma unroll
    for (int ot = 0; ot < 3; ++ot)
#pragma unroll
        for (int nt = 0; nt < 2; ++nt) acc[ot][nt] = (f32x4)0.f;

#pragma unroll
    for (int nt = 0; nt < 2; ++nt) {
        const short8 bh0 = *(const short8*)&sxh[nt * 16 + lr][lk];
        const short8 bh1 = *(const short8*)&sxh[nt * 16 + lr][32 + lk];
        const short8 bl0 = *(const short8*)&sxl[nt * 16 + lr][lk];
        const short8 bl1 = *(const short8*)&sxl[nt * 16 + lr][32 + lk];
#pragma unroll
        for (int ot = 0; ot < 3; ++ot) {
            f32x4 d = acc[ot][nt];
            d = __builtin_amdgcn_mfma_f32_16x16x32_bf16(ah[ot][0], bh0, d, 0, 0, 0);
            d = __builtin_amdgcn_mfma_f32_16x16x32_bf16(ah[ot][1], bh1, d, 0, 0, 0);
            d = __builtin_amdgcn_mfma_f32_16x16x32_bf16(ah[ot][0], bl0, d, 0, 0, 0);
            d = __builtin_amdgcn_mfma_f32_16x16x32_bf16(ah[ot][1], bl1, d, 0, 0, 0);
            d = __builtin_amdgcn_mfma_f32_16x16x32_bf16(al[ot][0], bh0, d, 0, 0, 0);
            d = __builtin_amdgcn_mfma_f32_16x16x32_bf16(al[ot][1], bh1, d, 0, 0, 0);
            acc[ot][nt] = d;
        }
    }

#pragma unroll
    for (int ot = 0; ot < 3; ++ot) {
        const int tile = wv * 3 + ot;
        const int m    = tile >> 2;
        const int ol0  = (tile & 3) * 16;
        float* ob = (m == 0) ? qb : (m == 1) ? kb : vb;
        float* basep = ob + b * CHW + ol0 * HW + n0;
#pragma unroll
        for (int nt = 0; nt < 2; ++nt)
#pragma unroll
            for (int r = 0; r < 4; ++r) {
                const int orow = (lane >> 4) * 4 + r;
                basep[orow * HW + nt * 16 + lr] = acc[ot][nt][r];
            }
    }
}

// ---------------------------------------------------------------------------
// Pass 2 (v6): attn, r16 structure with CHEAP STAGE: pow-2 slot mapping
// (row = s>>5, c2 = s&31 — no /36 magic-mul, no column predicate; only a
// row-granular g-bounds check remains) + separate 160-thread halo zero.
// q load hoisted above the stage to overlap.  Compute loop unchanged
// (raw v_exp, 2048 wgs = 32 waves/CU, XCD swizzle).
// ---------------------------------------------------------------------------
__global__ __launch_bounds__(256) void attn_kernel(
    const float* __restrict__ qb,
    const float* __restrict__ kb,
    const float* __restrict__ vb,
    const float* __restrict__ rel_h,
    const float* __restrict__ rel_w,
    float* __restrict__ out)
{
    __shared__ __align__(16) float sk[SROWS][SCOLS];
    __shared__ __align__(16) float sv[SROWS][SCOLS];

    const int bid = blockIdx.x;
    const int b   = bid & 7;           // XCD co-residency: batch = XCD
    const int u   = bid >> 3;          // 0..255: chan*4 + rowtile
    const int c   = u >> 2;
    const int pl  = b * C + c;
    const int h0  = (u & 3) * TROWS;
    const int t   = threadIdx.x;

    const int lr = t >> 4;             // local row 0..15
    const int w0 = (t & 15) << 2;      // col base 0,4,..,60
    const int h  = h0 + lr;

    // hoisted q load: latency hides under the stage
    const float4 qv = *(const float4*)(qb + pl * HW + h * W + w0);

    const float* kp = kb + pl * HW;
    const float* vp = vb + pl * HW;

    // ---- stage interior: 2 planes * 640 float2 slots (pow-2 mapping) ----
#pragma unroll
    for (int i = 0; i < 5; ++i) {
        const int s  = t + i * 256;          // 0..1279
        const int p  = (s >= 640);
        const int s2 = p ? s - 640 : s;
        const int row = s2 >> 5;             // 0..19
        const int c2  = s2 & 31;             // f2 slot within row
        const int g   = h0 + row - PAD;      // global row
        float2 val = make_float2(0.f, 0.f);
        if ((unsigned)g < (unsigned)H)
            val = *(const float2*)((p ? vp : kp) + g * W + c2 * 2);
        float* dst = (p ? &sv[0][0] : &sk[0][0]) + row * SCOLS + 2 + c2 * 2;
        *(float2*)dst = val;
    }
    // ---- halo ring zero: cols {0,1} and {66..71} of all 20 rows ----
    if (t < 160) {
        const int p   = (t >= 80);
        const int s   = p ? t - 80 : t;
        const int row = s >> 2;              // 0..19
        const int e   = s & 3;               // 0 -> col 0; 1..3 -> 66,68,70
        const int col = (e == 0) ? 0 : (64 + 2 * e);
        float* dst = (p ? &sv[0][0] : &sk[0][0]) + row * SCOLS + col;
        *(float2*)dst = make_float2(0.f, 0.f);
    }
    __syncthreads();

    const float qe[4] = {qv.x * LOG2E, qv.y * LOG2E, qv.z * LOG2E, qv.w * LOG2E};

    const bool is_h = (c < (C / 2));
    const float* rp = is_h ? (rel_h + c * K) : (rel_w + (c - C / 2) * K);
    float r[K];
#pragma unroll
    for (int u2 = 0; u2 < K; ++u2) r[u2] = rp[u2];

    float den[4] = {0.f, 0.f, 0.f, 0.f};
    float num[4] = {0.f, 0.f, 0.f, 0.f};

    if (is_h) {
#pragma unroll
        for (int i = 0; i < K; ++i) {
            const float4 ka = *(const float4*)&sk[lr + i][w0];
            const float4 kc = *(const float4*)&sk[lr + i][w0 + 4];
            const float4 va = *(const float4*)&sv[lr + i][w0];
            const float4 vc = *(const float4*)&sv[lr + i][w0 + 4];
            const float kr[8] = {ka.x, ka.y, ka.z, ka.w, kc.x, kc.y, kc.z, kc.w};
            const float vr[8] = {va.x, va.y, va.z, va.w, vc.x, vc.y, vc.z, vc.w};
            float qri[4];
#pragma unroll
            for (int px = 0; px < 4; ++px) qri[px] = qe[px] * r[i];
#pragma unroll
            for (int j = 0; j < K; ++j) {
#pragma unroll
                for (int px = 0; px < 4; ++px) {
                    const float e = fast_exp2(fmaf(qe[px], kr[px + j], qri[px]));
                    den[px] += e;
                    num[px] = fmaf(e, vr[px + j], num[px]);
                }
            }
        }
    } else {
        float qrj[4][K];
#pragma unroll
        for (int px = 0; px < 4; ++px)
#pragma unroll
            for (int j = 0; j < K; ++j) qrj[px][j] = qe[px] * r[j];
#pragma unroll
        for (int i = 0; i < K; ++i) {
            const float4 ka = *(const float4*)&sk[lr + i][w0];
            const float4 kc = *(const float4*)&sk[lr + i][w0 + 4];
            const float4 va = *(const float4*)&sv[lr + i][w0];
            const float4 vc = *(const float4*)&sv[lr + i][w0 + 4];
            const float kr[8] = {ka.x, ka.y, ka.z, ka.w, kc.x, kc.y, kc.z, kc.w};
            const float vr[8] = {va.x, va.y, va.z, va.w, vc.x, vc.y, vc.z, vc.w};
#pragma unroll
            for (int j = 0; j < K; ++j) {
#pragma unroll
                for (int px = 0; px < 4; ++px) {
                    const float e = fast_exp2(fmaf(qe[px], kr[px + j], qrj[px][j]));
                    den[px] += e;
                    num[px] = fmaf(e, vr[px + j], num[px]);
                }
            }
        }
    }

    float4 o;
    o.x = num[0] * __builtin_amdgcn_rcpf(den[0]);
    o.y = num[1] * __builtin_amdgcn_rcpf(den[1]);
    o.z = num[2] * __builtin_amdgcn_rcpf(den[2]);
    o.w = num[3] * __builtin_amdgcn_rcpf(den[3]);
    *(float4*)(out + pl * HW + h * W + w0) = o;
}

// ---------------------------------------------------------------------------
extern "C" void kernel_launch(void* const* d_in, const int* in_sizes, int n_in,
                              void* d_out, int out_size, void* d_ws, size_t ws_size,
                              hipStream_t stream)
{
    const float* x     = (const float*)d_in[0];
    const float* Wq    = (const float*)d_in[1];
    const float* Wk    = (const float*)d_in[2];
    const float* Wv    = (const float*)d_in[3];
    const float* rel_h = (const float*)d_in[4];
    const float* rel_w = (const float*)d_in[5];

    float* qb = (float*)d_ws;        // [B,C,64,64]  8 MB
    float* kb = qb + TOT;            // [B,C,64,64]  8 MB
    float* vb = kb + TOT;            // [B,C,64,64]  8 MB

    qkv_mfma<<<B * 128, 256, 0, stream>>>(x, Wq, Wk, Wv, qb, kb, vb);

    attn_kernel<<<B * C * 4, 256, 0, stream>>>(qb, kb, vb, rel_h, rel_w,
                                               (float*)d_out);
}